// Round 1
// baseline (191.059 us; speedup 1.0000x reference)
//
#include <hip/hip_runtime.h>

#define NPG 64
#define IN 16
#define DM 128
#define NOUT 64
#define EPG 4096
#define BN_EPS 1e-5f

// ---------------------------------------------------------------------------
// Grid-wide barrier for a 256-block co-resident grid.
// Counters pre-zeroed by hipMemsetAsync (workspace is poisoned each iter).
// Device-scope atomics + agent fences (per-XCD L2s are not coherent).
// Profiler replays without the memset see ctr>=256 and fall through (no hang).
// ---------------------------------------------------------------------------
__device__ __forceinline__ void gbar(unsigned* ctr) {
    __syncthreads();
    if (threadIdx.x == 0) {
        __threadfence();                                   // release: L2 writeback
        atomicAdd(ctr, 1u);
        while (atomicAdd(ctr, 0u) < 256u) __builtin_amdgcn_s_sleep(2);
        __threadfence();                                   // acquire: L1/L2 inv
    }
    __syncthreads();
}

// One MLP layer: 256 blocks = 128 f-cols x 2 graph-halves (same as old k_mlp).
__device__ void mlp_phase(float* u,
    const float* __restrict__ vin, const float* __restrict__ statsin,
    const float* __restrict__ gbn, const float* __restrict__ bbn,
    const float* __restrict__ W, const float* __restrict__ bias,
    float* __restrict__ vout, float* __restrict__ statsout)
{
    float* scale_s = u;          // 128
    float* shift_s = u + 128;    // 128
    float* wcol    = u + 256;    // 128
    float* pc      = u + 384;    // 256
    float* h_s     = u + 640;    // 64*129
    const int b = blockIdx.x, t = threadIdx.x;
    const int f = b & 127, gh = b >> 7;
    if (t < 128) {
        float s1 = statsin[t * 2], s2 = statsin[t * 2 + 1];
        float m = s1 * (1.f / 128.f);
        float var = s2 * (1.f / 128.f) - m * m;
        float sc = gbn[t] * rsqrtf(var + BN_EPS);
        scale_s[t] = sc;
        shift_s[t] = bbn[t] - m * sc;
        wcol[t] = W[t * 128 + f];
    }
    __syncthreads();
    const int g0r = gh * 64;
    const float4* vin4 = (const float4*)(vin + g0r * 128);
    #pragma unroll
    for (int it = 0; it < 8; ++it) {
        int idx = it * 256 + t;            // 2048 float4 = 64 rows x 128
        int gl = idx >> 5, k4 = (idx & 31) * 4;
        float4 vv = vin4[idx];
        float* hp = h_s + gl * 129 + k4;
        hp[0] = vv.x * scale_s[k4 + 0] + shift_s[k4 + 0];
        hp[1] = vv.y * scale_s[k4 + 1] + shift_s[k4 + 1];
        hp[2] = vv.z * scale_s[k4 + 2] + shift_s[k4 + 2];
        hp[3] = vv.w * scale_s[k4 + 3] + shift_s[k4 + 3];
    }
    __syncthreads();
    {
        const int gl = t & 63, kh = t >> 6;
        float acc = 0.f;
        #pragma unroll 8
        for (int k = kh * 32; k < kh * 32 + 32; ++k) acc += h_s[gl * 129 + k] * wcol[k];
        pc[gl * 4 + kh] = acc;
    }
    __syncthreads();
    if (t < 64) {   // wave 0
        float v = fmaxf(pc[t * 4] + pc[t * 4 + 1] + pc[t * 4 + 2] + pc[t * 4 + 3]
                        + bias[f], 0.f);
        vout[(size_t)(g0r + t) * 128 + f] = v;
        float s1 = v, s2 = v * v;
        #pragma unroll
        for (int off = 32; off > 0; off >>= 1) {
            s1 += __shfl_down(s1, off, 64);
            s2 += __shfl_down(s2, off, 64);
        }
        if (t == 0) {
            atomicAdd(&statsout[f * 2], s1);
            atomicAdd(&statsout[f * 2 + 1], s2);
        }
    }
}

// ---------------------------------------------------------------------------
// Single fused kernel: F (conv+gemm) | R (reduce+bn0) | M1 | M2 | O,
// separated by 4 grid barriers. 256 blocks x 256 threads, 63 KB LDS
// (<=2 blocks/CU -> all 256 blocks resident -> spin barrier is safe).
// ---------------------------------------------------------------------------
__global__ __launch_bounds__(256) void k_fused(
    const float* __restrict__ x, const float* __restrict__ ew,
    const float* __restrict__ W1, const float* __restrict__ b1,
    const float* __restrict__ W2, const float* __restrict__ b2,
    const float* __restrict__ Wm0, const float* __restrict__ bm0,
    const float* __restrict__ gbn0, const float* __restrict__ bbn0,
    const float* __restrict__ Wm1, const float* __restrict__ bm1,
    const float* __restrict__ gbn1, const float* __restrict__ bbn1,
    const float* __restrict__ Wm2, const float* __restrict__ bm2,
    const float* __restrict__ gbn2, const float* __restrict__ bbn2,
    const float* __restrict__ Wo, const float* __restrict__ bo,
    float* __restrict__ ws, float* __restrict__ out)
{
    __shared__ __align__(16) float u[16128];   // 63KB union, reused per phase
    unsigned* bar = (unsigned*)ws;             // 4 counters, 64B apart (memset 0)
    float* stats = ws + 256;                   // 768 floats (memset 0)
    float* part  = ws + 1024;                  // 128*8192
    float* ppart = part + 128 * 8192;          // 16384
    float* v0 = ppart + 16384;
    float* v1 = v0 + 16384;
    float* v2 = v1 + 16384;
    const int bid = blockIdx.x, t = threadIdx.x;

    // ======================= phase F =======================
    if (bid < 128) {
        // ---------------- conv path (one block per graph) ----------------
        float* ew_s     = u;             // [i][j] 4096 (raw)
        float* x_s      = u + 4096;      // x^T [k][i] 1024
        float* W1_s     = u + 5120;      // [k][f] 2048
        float* P_s      = u + 7168;      // [i][f] 8192 (dinv_i * P)
        float* b1_s     = u + 15360;     // 128
        float* dinv_s   = u + 15488;     // 64
        float* t_s      = u + 15552;     // 64
        float* zp       = u + 4096;      // overlay (x_s/W1_s dead): 16*132
        float* z_full   = u + 15616;     // 128
        float* pooled_s = u + 15744;     // 128
        float* pp2      = u + 15872;     // 256
        const int g = bid;
        {
            const float4* ew4 = (const float4*)(ew + g * EPG);
            float4* ews4 = (float4*)ew_s;
            #pragma unroll
            for (int i = 0; i < 4; i++) ews4[t + 256 * i] = ew4[t + 256 * i];
            const int xi = t & 63, k4 = (t >> 6) * 4;
            float4 xv = *(const float4*)(x + g * NPG * IN + xi * IN + k4);
            x_s[(k4 + 0) * 64 + xi] = xv.x;
            x_s[(k4 + 1) * 64 + xi] = xv.y;
            x_s[(k4 + 2) * 64 + xi] = xv.z;
            x_s[(k4 + 3) * 64 + xi] = xv.w;
            ((float4*)W1_s)[t]       = ((const float4*)W1)[t];
            ((float4*)W1_s)[t + 256] = ((const float4*)W1)[t + 256];
            if (t < 128) b1_s[t] = b1[t];
        }
        __syncthreads();

        if (t < NPG) {
            float s = 0.f;
            #pragma unroll 8
            for (int i = 0; i < NPG; i++) s += ew_s[i * NPG + t];
            dinv_s[t] = (s > 0.f) ? rsqrtf(s) : 0.f;
        }
        __syncthreads();

        {   // t_s[i] = dinv_i * (sum_j ew[i,j] dinv_j) / 64
            const int j = t & 63, q = t >> 6;
            const float dj = dinv_s[j];
            for (int i = q * 16; i < q * 16 + 16; i++) {
                float vv = ew_s[i * NPG + j] * dj;
                #pragma unroll
                for (int off = 32; off > 0; off >>= 1) vv += __shfl_down(vv, off, 64);
                if (j == 0) t_s[i] = dinv_s[i] * vv * (1.f / 64.f);
            }
        }

        {   // P' = dinv_i * (x @ W1)
            const int it = t & 15, ft = t >> 4;
            const int i0 = it * 4, f0 = ft * 8;
            float accp[4][8];
            #pragma unroll
            for (int a = 0; a < 4; a++)
                #pragma unroll
                for (int c = 0; c < 8; c++) accp[a][c] = 0.f;
            #pragma unroll
            for (int k = 0; k < IN; k++) {
                const float4 a4  = *(const float4*)(x_s + k * 64 + i0);
                const float4 b0v = *(const float4*)(W1_s + k * DM + f0);
                const float4 b1v = *(const float4*)(W1_s + k * DM + f0 + 4);
                const float av[4] = {a4.x, a4.y, a4.z, a4.w};
                const float bv[8] = {b0v.x, b0v.y, b0v.z, b0v.w, b1v.x, b1v.y, b1v.z, b1v.w};
                #pragma unroll
                for (int a = 0; a < 4; a++)
                    #pragma unroll
                    for (int c = 0; c < 8; c++) accp[a][c] += av[a] * bv[c];
            }
            #pragma unroll
            for (int a = 0; a < 4; a++) {
                const float di = dinv_s[i0 + a];
                float4* o = (float4*)(P_s + (i0 + a) * DM + f0);
                o[0] = make_float4(di * accp[a][0], di * accp[a][1],
                                   di * accp[a][2], di * accp[a][3]);
                o[1] = make_float4(di * accp[a][4], di * accp[a][5],
                                   di * accp[a][6], di * accp[a][7]);
            }
        }
        __syncthreads();

        {   // aggregation + z-partials
            const int jt = t & 15, ft = t >> 4;
            const int j0 = jt * 4, f0 = ft * 8;
            float acc[4][8];
            #pragma unroll
            for (int a = 0; a < 4; a++)
                #pragma unroll
                for (int c = 0; c < 8; c++) acc[a][c] = 0.f;
            #pragma unroll 4
            for (int k = 0; k < 64; k++) {
                const float4 a4  = *(const float4*)(ew_s + k * 64 + j0);
                const float4 b0v = *(const float4*)(P_s + k * DM + f0);
                const float4 b1v = *(const float4*)(P_s + k * DM + f0 + 4);
                const float av[4] = {a4.x, a4.y, a4.z, a4.w};
                const float bv[8] = {b0v.x, b0v.y, b0v.z, b0v.w, b1v.x, b1v.y, b1v.z, b1v.w};
                #pragma unroll
                for (int a = 0; a < 4; a++)
                    #pragma unroll
                    for (int c = 0; c < 8; c++) acc[a][c] += av[a] * bv[c];
            }
            float zpart[8];
            #pragma unroll
            for (int c = 0; c < 8; c++) zpart[c] = 0.f;
            #pragma unroll
            for (int a = 0; a < 4; a++) {
                const float dj = dinv_s[j0 + a], tj = t_s[j0 + a];
                #pragma unroll
                for (int c = 0; c < 8; c++) {
                    float h = fmaxf(dj * acc[a][c] + b1_s[f0 + c], 0.f);
                    zpart[c] += tj * h;
                }
            }
            float4* zo = (float4*)(zp + jt * 132 + f0);
            zo[0] = make_float4(zpart[0], zpart[1], zpart[2], zpart[3]);
            zo[1] = make_float4(zpart[4], zpart[5], zpart[6], zpart[7]);
        }
        __syncthreads();

        if (t < 128) {
            float s = 0.f;
            #pragma unroll
            for (int jt = 0; jt < 16; jt++) s += zp[jt * 132 + t];
            z_full[t] = s;
        }
        __syncthreads();

        {   // pooled = relu(z @ W2 + b2)
            const int c = t & 127, kh = t >> 7;
            float acc = 0.f;
            #pragma unroll 8
            for (int k = kh * 64; k < kh * 64 + 64; k++)
                acc += z_full[k] * W2[k * DM + c];
            pp2[kh * 128 + c] = acc;
        }
        __syncthreads();
        if (t < 128) pooled_s[t] = fmaxf(pp2[t] + pp2[128 + t] + b2[t], 0.f);
        __syncthreads();

        {   // ppart = pooled @ Wm0[0:128,:]
            const int f = t & 127, kh = t >> 7;
            float acc = 0.f;
            #pragma unroll 8
            for (int k = kh * 64; k < kh * 64 + 64; k++)
                acc += pooled_s[k] * Wm0[k * DM + f];
            pp2[kh * 128 + f] = acc;
        }
        __syncthreads();
        if (t < 128) ppart[g * DM + t] = pp2[t] + pp2[128 + t];
    } else {
        // ---------------- gemm x/ew chunk path (K=80) ----------------
        // register-batched float4 staging: all loads in flight before LDS writes
        const int c = bid - 128;
        const int kc = c >> 1, fh = c & 1;
        const int K0 = kc * 80;
        float* a_s = u;                  // [k][g] 80*132
        float* b_s = u + 10560;          // [k][fl] 80*64

        float4 va[8], vb2[2], vc[5];
        #pragma unroll
        for (int it = 0; it < 8; it++) {             // k 0..63: 2048 float4
            int idx = it * 256 + t;
            int gg = idx >> 4, k4 = (idx & 15) << 2;
            int K = K0 + k4;
            const float* src = (K < 1024) ? (x + gg * 1024 + K)
                                          : (ew + gg * 4096 + (K - 1024));
            va[it] = *(const float4*)src;
        }
        #pragma unroll
        for (int it = 0; it < 2; it++) {             // k 64..79: 512 float4
            int idx = it * 256 + t;
            int gg = idx >> 2, k4 = 64 + ((idx & 3) << 2);
            int K = K0 + k4;
            const float* src = (K < 1024) ? (x + gg * 1024 + K)
                                          : (ew + gg * 4096 + (K - 1024));
            vb2[it] = *(const float4*)src;
        }
        #pragma unroll
        for (int it = 0; it < 5; it++) {             // Wm0 slice: 1280 float4
            int idx = it * 256 + t;
            int k = idx >> 4, fl4 = (idx & 15) << 2;
            vc[it] = *(const float4*)(Wm0 + (size_t)(128 + K0 + k) * 128 + fh * 64 + fl4);
        }
        #pragma unroll
        for (int it = 0; it < 8; it++) {
            int idx = it * 256 + t;
            int gg = idx >> 4, k4 = (idx & 15) << 2;
            a_s[(k4 + 0) * 132 + gg] = fmaxf(va[it].x, 0.f);
            a_s[(k4 + 1) * 132 + gg] = fmaxf(va[it].y, 0.f);
            a_s[(k4 + 2) * 132 + gg] = fmaxf(va[it].z, 0.f);
            a_s[(k4 + 3) * 132 + gg] = fmaxf(va[it].w, 0.f);
        }
        #pragma unroll
        for (int it = 0; it < 2; it++) {
            int idx = it * 256 + t;
            int gg = idx >> 2, k4 = 64 + ((idx & 3) << 2);
            a_s[(k4 + 0) * 132 + gg] = fmaxf(vb2[it].x, 0.f);
            a_s[(k4 + 1) * 132 + gg] = fmaxf(vb2[it].y, 0.f);
            a_s[(k4 + 2) * 132 + gg] = fmaxf(vb2[it].z, 0.f);
            a_s[(k4 + 3) * 132 + gg] = fmaxf(vb2[it].w, 0.f);
        }
        #pragma unroll
        for (int it = 0; it < 5; it++) {
            int idx = it * 256 + t;
            int k = idx >> 4, fl4 = (idx & 15) << 2;
            *(float4*)(b_s + k * 64 + fl4) = vc[it];
        }
        __syncthreads();

        const int gthr = t & 31, fthr = t >> 5;   // 32 x 8
        const int g0 = gthr * 4, f0 = fthr * 8;
        float acc[4][8];
        #pragma unroll
        for (int i = 0; i < 4; i++)
            #pragma unroll
            for (int jx = 0; jx < 8; jx++) acc[i][jx] = 0.f;

        #pragma unroll 4
        for (int k = 0; k < 80; k++) {
            const float4 a4  = *(const float4*)(a_s + k * 132 + g0);
            const float4 c0v = *(const float4*)(b_s + k * 64 + f0);
            const float4 c1v = *(const float4*)(b_s + k * 64 + f0 + 4);
            const float av[4] = {a4.x, a4.y, a4.z, a4.w};
            const float bv[8] = {c0v.x, c0v.y, c0v.z, c0v.w, c1v.x, c1v.y, c1v.z, c1v.w};
            #pragma unroll
            for (int i = 0; i < 4; i++)
                #pragma unroll
                for (int jx = 0; jx < 8; jx++) acc[i][jx] += av[i] * bv[jx];
        }

        float* pp = part + (size_t)c * 8192;
        #pragma unroll
        for (int i = 0; i < 4; i++) {
            float4* o = (float4*)(pp + (g0 + i) * 64 + f0);
            o[0] = make_float4(acc[i][0], acc[i][1], acc[i][2], acc[i][3]);
            o[1] = make_float4(acc[i][4], acc[i][5], acc[i][6], acc[i][7]);
        }
    }
    gbar(bar + 0);

    // ======================= phase R: reduce + bn0 =======================
    {
        float* r1  = u;          // 1024
        float* sv  = u + 1024;   // 64
        float* sv2 = u + 1088;   // 64
        const int fgrp = bid & 7, gt = bid >> 3;
        const int f4 = t & 3, gl = (t >> 2) & 3, ch = t >> 4;
        const int g = gt * 4 + gl;
        const int fbase = fgrp * 16 + f4 * 4;
        const int fh = fbase >> 6, fl = fbase & 63;
        const float4* p = (const float4*)part
                        + ((size_t)(2 * (ch * 4) + fh) * 8192 + g * 64 + fl) / 4;
        float4 v = make_float4(0.f, 0.f, 0.f, 0.f);
        #pragma unroll
        for (int cc = 0; cc < 4; cc++) {
            float4 x4 = p[(size_t)cc * 4096];
            v.x += x4.x; v.y += x4.y; v.z += x4.z; v.w += x4.w;
        }
        float* r = r1 + ch * 64 + gl * 16 + f4 * 4;
        r[0] = v.x; r[1] = v.y; r[2] = v.z; r[3] = v.w;
        __syncthreads();

        if (t < 64) {
            const int fsub = t & 15, gl2 = t >> 4;
            const int f = fgrp * 16 + fsub, gg = gt * 4 + gl2;
            float s = bm0[f] + ppart[gg * DM + f];
            #pragma unroll
            for (int c2 = 0; c2 < 16; c2++) s += r1[c2 * 64 + gl2 * 16 + fsub];
            s = fmaxf(s, 0.f);
            v0[gg * DM + f] = s;
            sv[t] = s; sv2[t] = s * s;
        }
        __syncthreads();
        if (t < 16) {
            float s1 = sv[t] + sv[t + 16] + sv[t + 32] + sv[t + 48];
            float s2 = sv2[t] + sv2[t + 16] + sv2[t + 32] + sv2[t + 48];
            atomicAdd(&stats[(fgrp * 16 + t) * 2], s1);
            atomicAdd(&stats[(fgrp * 16 + t) * 2 + 1], s2);
        }
    }
    gbar(bar + 16);

    // ======================= phases M1, M2 =======================
    mlp_phase(u, v0, stats,       gbn0, bbn0, Wm1, bm1, v1, stats + 256);
    gbar(bar + 32);
    mlp_phase(u, v1, stats + 256, gbn1, bbn1, Wm2, bm2, v2, stats + 512);
    gbar(bar + 48);

    // ======================= phase O: output layer =======================
    if (bid < 32) {
        float* Wo_s    = u;           // 8192 (32KB)
        float* vrow    = u + 8192;    // 4*128
        float* scale_s = u + 8704;    // 128
        float* shift_s = u + 8832;    // 128
        const float* st2 = stats + 512;
        const int gq = bid * 4;       // 4 graphs per block
        if (t < 128) {
            float s1 = st2[t * 2], s2 = st2[t * 2 + 1];
            float m = s1 * (1.f / 128.f);
            float var = s2 * (1.f / 128.f) - m * m;
            float sc = gbn2[t] * rsqrtf(var + BN_EPS);
            scale_s[t] = sc;
            shift_s[t] = bbn2[t] - m * sc;
        }
        __syncthreads();
        {
            const float4* wo4 = (const float4*)Wo;
            float4* wos4 = (float4*)Wo_s;
            #pragma unroll
            for (int it = 0; it < 8; it++) wos4[it * 256 + t] = wo4[it * 256 + t];
        }
        if (t < 128) {
            const int r = t >> 5, k4 = (t & 31) * 4;
            float4 vv = ((const float4*)(v2 + gq * 128))[t];
            vrow[r * 128 + k4 + 0] = vv.x * scale_s[k4 + 0] + shift_s[k4 + 0];
            vrow[r * 128 + k4 + 1] = vv.y * scale_s[k4 + 1] + shift_s[k4 + 1];
            vrow[r * 128 + k4 + 2] = vv.z * scale_s[k4 + 2] + shift_s[k4 + 2];
            vrow[r * 128 + k4 + 3] = vv.w * scale_s[k4 + 3] + shift_s[k4 + 3];
        }
        __syncthreads();
        const int g2 = t >> 6, o = t & 63;
        float acc = bo[o];
        #pragma unroll 8
        for (int k = 0; k < 128; k++) acc += vrow[g2 * 128 + k] * Wo_s[k * 64 + o];
        out[(gq + g2) * NOUT + o] = acc;
    }
}

extern "C" void kernel_launch(void* const* d_in, const int* in_sizes, int n_in,
                              void* d_out, int out_size, void* d_ws, size_t ws_size,
                              hipStream_t stream)
{
    const float* x   = (const float*)d_in[0];
    const float* ew  = (const float*)d_in[2];
    const float* W1  = (const float*)d_in[4];
    const float* b1  = (const float*)d_in[5];
    const float* W2  = (const float*)d_in[6];
    const float* b2  = (const float*)d_in[7];
    const float* Wm0 = (const float*)d_in[8];
    const float* bm0 = (const float*)d_in[9];
    const float* g0  = (const float*)d_in[10];
    const float* be0 = (const float*)d_in[11];
    const float* Wm1 = (const float*)d_in[12];
    const float* bm1 = (const float*)d_in[13];
    const float* g1  = (const float*)d_in[14];
    const float* be1 = (const float*)d_in[15];
    const float* Wm2 = (const float*)d_in[16];
    const float* bm2 = (const float*)d_in[17];
    const float* g2  = (const float*)d_in[18];
    const float* be2 = (const float*)d_in[19];
    const float* Wo  = (const float*)d_in[20];
    const float* bo  = (const float*)d_in[21];

    float* ws = (float*)d_ws;
    // zero barrier counters (bytes 0..255) + BN stats (floats 256..1023)
    hipMemsetAsync(d_ws, 0, 4096, stream);
    k_fused<<<256, 256, 0, stream>>>(x, ew, W1, b1, W2, b2,
                                     Wm0, bm0, g0, be0,
                                     Wm1, bm1, g1, be1,
                                     Wm2, bm2, g2, be2,
                                     Wo, bo, ws, (float*)d_out);
}

// Round 2
// 150.402 us; speedup vs baseline: 1.2703x; 1.2703x over previous
//
#include <hip/hip_runtime.h>

#define NPG 64
#define IN 16
#define DM 128
#define NOUT 64
#define EPG 4096
#define BN_EPS 1e-5f

// ---------------------------------------------------------------------------
// Barrier plumbing. ws unsigned layout (first 4 KB, memset to 0 each launch):
//   subcnt[g]  at u32 ofs g*16   (g=0..7)   - phase-F arrival sub-counters
//   root       at u32 ofs 128
//   tcnt[k]    at u32 ofs 144+16k (k=0..2)  - tail barrier counters
//   flags[i]   at u32 ofs 256+16i (i=0..31) - per-tail-block release lines
// Arrivals are RMW on spread lines; spins are agent-scope LOADS on private
// lines with s_sleep backoff -> no same-line RMW storm (round-1 lesson).
// Profiler replays without the memset see flags >= epoch and fall through.
// ---------------------------------------------------------------------------
__device__ __forceinline__ void tail_bar(unsigned* cnt, unsigned* flags,
                                         unsigned epoch, int bid) {
    __syncthreads();
    if (threadIdx.x == 0) {
        __threadfence();                       // release
        unsigned old = atomicAdd(cnt, 1u);
        if (old == 31u) {
            __threadfence();
            #pragma unroll
            for (int i = 0; i < 32; i++)
                __hip_atomic_store(&flags[i * 16], epoch,
                                   __ATOMIC_RELAXED, __HIP_MEMORY_SCOPE_AGENT);
        }
        while (__hip_atomic_load(&flags[bid * 16],
                                 __ATOMIC_RELAXED, __HIP_MEMORY_SCOPE_AGENT) < epoch)
            __builtin_amdgcn_s_sleep(8);
        __threadfence();                       // acquire
    }
    __syncthreads();
}

// ---------------------------------------------------------------------------
// Fused kernel: F (conv+gemm, 256 blocks) | big barrier (224 arrive-and-exit)
// | tail R+M1+M2+O in 32 blocks (4 graphs each) with 3 small barriers.
// ---------------------------------------------------------------------------
__global__ __launch_bounds__(256) void k_fused(
    const float* __restrict__ x, const float* __restrict__ ew,
    const float* __restrict__ W1, const float* __restrict__ b1,
    const float* __restrict__ W2, const float* __restrict__ b2,
    const float* __restrict__ Wm0, const float* __restrict__ bm0,
    const float* __restrict__ gbn0, const float* __restrict__ bbn0,
    const float* __restrict__ Wm1, const float* __restrict__ bm1,
    const float* __restrict__ gbn1, const float* __restrict__ bbn1,
    const float* __restrict__ Wm2, const float* __restrict__ bm2,
    const float* __restrict__ gbn2, const float* __restrict__ bbn2,
    const float* __restrict__ Wo, const float* __restrict__ bo,
    float* __restrict__ ws, float* __restrict__ out)
{
    __shared__ __align__(16) float u[16128];   // 63KB union, reused per phase
    unsigned* bu    = (unsigned*)ws;
    unsigned* subcnt = bu;                     // 8 x stride16
    unsigned* root   = bu + 128;
    unsigned* tcnt   = bu + 144;               // 3 x stride16
    unsigned* flags  = bu + 256;               // 32 x stride16
    float* part   = ws + 1024;                 // 128*8192
    float* ppart  = part + 128 * 8192;         // 128*128
    float* spart0 = ppart + 16384;             // 32*256
    float* spart1 = spart0 + 8192;             // 32*256
    float* spart2 = spart1 + 8192;             // 32*256
    const int bid = blockIdx.x, t = threadIdx.x;

    // ======================= phase F =======================
    if (bid < 128) {
        // ---------------- conv path (one block per graph) ----------------
        float* ew_s     = u;             // [i][j] 4096 (raw)
        float* x_s      = u + 4096;      // x^T [k][i] 1024
        float* W1_s     = u + 5120;      // [k][f] 2048
        float* P_s      = u + 7168;      // [i][f] 8192 (dinv_i * P)
        float* b1_s     = u + 15360;     // 128
        float* dinv_s   = u + 15488;     // 64
        float* t_s      = u + 15552;     // 64
        float* zp       = u + 4096;      // overlay (x_s/W1_s dead): 16*132
        float* z_full   = u + 15616;     // 128
        float* pooled_s = u + 15744;     // 128
        float* pp2      = u + 15872;     // 256
        const int g = bid;
        {
            const float4* ew4 = (const float4*)(ew + g * EPG);
            float4* ews4 = (float4*)ew_s;
            #pragma unroll
            for (int i = 0; i < 4; i++) ews4[t + 256 * i] = ew4[t + 256 * i];
            const int xi = t & 63, k4 = (t >> 6) * 4;
            float4 xv = *(const float4*)(x + g * NPG * IN + xi * IN + k4);
            x_s[(k4 + 0) * 64 + xi] = xv.x;
            x_s[(k4 + 1) * 64 + xi] = xv.y;
            x_s[(k4 + 2) * 64 + xi] = xv.z;
            x_s[(k4 + 3) * 64 + xi] = xv.w;
            ((float4*)W1_s)[t]       = ((const float4*)W1)[t];
            ((float4*)W1_s)[t + 256] = ((const float4*)W1)[t + 256];
            if (t < 128) b1_s[t] = b1[t];
        }
        __syncthreads();

        if (t < NPG) {
            float s = 0.f;
            #pragma unroll 8
            for (int i = 0; i < NPG; i++) s += ew_s[i * NPG + t];
            dinv_s[t] = (s > 0.f) ? rsqrtf(s) : 0.f;
        }
        __syncthreads();

        {   // t_s[i] = dinv_i * (sum_j ew[i,j] dinv_j) / 64
            const int j = t & 63, q = t >> 6;
            const float dj = dinv_s[j];
            for (int i = q * 16; i < q * 16 + 16; i++) {
                float vv = ew_s[i * NPG + j] * dj;
                #pragma unroll
                for (int off = 32; off > 0; off >>= 1) vv += __shfl_down(vv, off, 64);
                if (j == 0) t_s[i] = dinv_s[i] * vv * (1.f / 64.f);
            }
        }

        {   // P' = dinv_i * (x @ W1)
            const int it = t & 15, ft = t >> 4;
            const int i0 = it * 4, f0 = ft * 8;
            float accp[4][8];
            #pragma unroll
            for (int a = 0; a < 4; a++)
                #pragma unroll
                for (int c = 0; c < 8; c++) accp[a][c] = 0.f;
            #pragma unroll
            for (int k = 0; k < IN; k++) {
                const float4 a4  = *(const float4*)(x_s + k * 64 + i0);
                const float4 b0v = *(const float4*)(W1_s + k * DM + f0);
                const float4 b1v = *(const float4*)(W1_s + k * DM + f0 + 4);
                const float av[4] = {a4.x, a4.y, a4.z, a4.w};
                const float bv[8] = {b0v.x, b0v.y, b0v.z, b0v.w, b1v.x, b1v.y, b1v.z, b1v.w};
                #pragma unroll
                for (int a = 0; a < 4; a++)
                    #pragma unroll
                    for (int c = 0; c < 8; c++) accp[a][c] += av[a] * bv[c];
            }
            #pragma unroll
            for (int a = 0; a < 4; a++) {
                const float di = dinv_s[i0 + a];
                float4* o = (float4*)(P_s + (i0 + a) * DM + f0);
                o[0] = make_float4(di * accp[a][0], di * accp[a][1],
                                   di * accp[a][2], di * accp[a][3]);
                o[1] = make_float4(di * accp[a][4], di * accp[a][5],
                                   di * accp[a][6], di * accp[a][7]);
            }
        }
        __syncthreads();

        {   // aggregation + z-partials
            const int jt = t & 15, ft = t >> 4;
            const int j0 = jt * 4, f0 = ft * 8;
            float acc[4][8];
            #pragma unroll
            for (int a = 0; a < 4; a++)
                #pragma unroll
                for (int c = 0; c < 8; c++) acc[a][c] = 0.f;
            #pragma unroll 4
            for (int k = 0; k < 64; k++) {
                const float4 a4  = *(const float4*)(ew_s + k * 64 + j0);
                const float4 b0v = *(const float4*)(P_s + k * DM + f0);
                const float4 b1v = *(const float4*)(P_s + k * DM + f0 + 4);
                const float av[4] = {a4.x, a4.y, a4.z, a4.w};
                const float bv[8] = {b0v.x, b0v.y, b0v.z, b0v.w, b1v.x, b1v.y, b1v.z, b1v.w};
                #pragma unroll
                for (int a = 0; a < 4; a++)
                    #pragma unroll
                    for (int c = 0; c < 8; c++) acc[a][c] += av[a] * bv[c];
            }
            float zpart[8];
            #pragma unroll
            for (int c = 0; c < 8; c++) zpart[c] = 0.f;
            #pragma unroll
            for (int a = 0; a < 4; a++) {
                const float dj = dinv_s[j0 + a], tj = t_s[j0 + a];
                #pragma unroll
                for (int c = 0; c < 8; c++) {
                    float h = fmaxf(dj * acc[a][c] + b1_s[f0 + c], 0.f);
                    zpart[c] += tj * h;
                }
            }
            float4* zo = (float4*)(zp + jt * 132 + f0);
            zo[0] = make_float4(zpart[0], zpart[1], zpart[2], zpart[3]);
            zo[1] = make_float4(zpart[4], zpart[5], zpart[6], zpart[7]);
        }
        __syncthreads();

        if (t < 128) {
            float s = 0.f;
            #pragma unroll
            for (int jt = 0; jt < 16; jt++) s += zp[jt * 132 + t];
            z_full[t] = s;
        }
        __syncthreads();

        {   // pooled = relu(z @ W2 + b2)
            const int c = t & 127, kh = t >> 7;
            float acc = 0.f;
            #pragma unroll 8
            for (int k = kh * 64; k < kh * 64 + 64; k++)
                acc += z_full[k] * W2[k * DM + c];
            pp2[kh * 128 + c] = acc;
        }
        __syncthreads();
        if (t < 128) pooled_s[t] = fmaxf(pp2[t] + pp2[128 + t] + b2[t], 0.f);
        __syncthreads();

        {   // ppart = pooled @ Wm0[0:128,:]
            const int f = t & 127, kh = t >> 7;
            float acc = 0.f;
            #pragma unroll 8
            for (int k = kh * 64; k < kh * 64 + 64; k++)
                acc += pooled_s[k] * Wm0[k * DM + f];
            pp2[kh * 128 + f] = acc;
        }
        __syncthreads();
        if (t < 128) ppart[g * DM + t] = pp2[t] + pp2[128 + t];
    } else {
        // ---------------- gemm x/ew chunk path (K=80) ----------------
        const int c = bid - 128;
        const int kc = c >> 1, fh = c & 1;
        const int K0 = kc * 80;
        float* a_s = u;                  // [k][g] 80*132
        float* b_s = u + 10560;          // [k][fl] 80*64

        float4 va[8], vb2[2], vc[5];
        #pragma unroll
        for (int it = 0; it < 8; it++) {             // k 0..63: 2048 float4
            int idx = it * 256 + t;
            int gg = idx >> 4, k4 = (idx & 15) << 2;
            int K = K0 + k4;
            const float* src = (K < 1024) ? (x + gg * 1024 + K)
                                          : (ew + gg * 4096 + (K - 1024));
            va[it] = *(const float4*)src;
        }
        #pragma unroll
        for (int it = 0; it < 2; it++) {             // k 64..79: 512 float4
            int idx = it * 256 + t;
            int gg = idx >> 2, k4 = 64 + ((idx & 3) << 2);
            int K = K0 + k4;
            const float* src = (K < 1024) ? (x + gg * 1024 + K)
                                          : (ew + gg * 4096 + (K - 1024));
            vb2[it] = *(const float4*)src;
        }
        #pragma unroll
        for (int it = 0; it < 5; it++) {             // Wm0 slice: 1280 float4
            int idx = it * 256 + t;
            int k = idx >> 4, fl4 = (idx & 15) << 2;
            vc[it] = *(const float4*)(Wm0 + (size_t)(128 + K0 + k) * 128 + fh * 64 + fl4);
        }
        #pragma unroll
        for (int it = 0; it < 8; it++) {
            int idx = it * 256 + t;
            int gg = idx >> 4, k4 = (idx & 15) << 2;
            a_s[(k4 + 0) * 132 + gg] = fmaxf(va[it].x, 0.f);
            a_s[(k4 + 1) * 132 + gg] = fmaxf(va[it].y, 0.f);
            a_s[(k4 + 2) * 132 + gg] = fmaxf(va[it].z, 0.f);
            a_s[(k4 + 3) * 132 + gg] = fmaxf(va[it].w, 0.f);
        }
        #pragma unroll
        for (int it = 0; it < 2; it++) {
            int idx = it * 256 + t;
            int gg = idx >> 2, k4 = 64 + ((idx & 3) << 2);
            a_s[(k4 + 0) * 132 + gg] = fmaxf(vb2[it].x, 0.f);
            a_s[(k4 + 1) * 132 + gg] = fmaxf(vb2[it].y, 0.f);
            a_s[(k4 + 2) * 132 + gg] = fmaxf(vb2[it].z, 0.f);
            a_s[(k4 + 3) * 132 + gg] = fmaxf(vb2[it].w, 0.f);
        }
        #pragma unroll
        for (int it = 0; it < 5; it++) {
            int idx = it * 256 + t;
            int k = idx >> 4, fl4 = (idx & 15) << 2;
            *(float4*)(b_s + k * 64 + fl4) = vc[it];
        }
        __syncthreads();

        const int gthr = t & 31, fthr = t >> 5;   // 32 x 8
        const int g0 = gthr * 4, f0 = fthr * 8;
        float acc[4][8];
        #pragma unroll
        for (int i = 0; i < 4; i++)
            #pragma unroll
            for (int jx = 0; jx < 8; jx++) acc[i][jx] = 0.f;

        #pragma unroll 4
        for (int k = 0; k < 80; k++) {
            const float4 a4  = *(const float4*)(a_s + k * 132 + g0);
            const float4 c0v = *(const float4*)(b_s + k * 64 + f0);
            const float4 c1v = *(const float4*)(b_s + k * 64 + f0 + 4);
            const float av[4] = {a4.x, a4.y, a4.z, a4.w};
            const float bv[8] = {c0v.x, c0v.y, c0v.z, c0v.w, c1v.x, c1v.y, c1v.z, c1v.w};
            #pragma unroll
            for (int i = 0; i < 4; i++)
                #pragma unroll
                for (int jx = 0; jx < 8; jx++) acc[i][jx] += av[i] * bv[jx];
        }

        float* pp = part + (size_t)c * 8192;
        #pragma unroll
        for (int i = 0; i < 4; i++) {
            float4* o = (float4*)(pp + (g0 + i) * 64 + f0);
            o[0] = make_float4(acc[i][0], acc[i][1], acc[i][2], acc[i][3]);
            o[1] = make_float4(acc[i][4], acc[i][5], acc[i][6], acc[i][7]);
        }
    }

    // ============== barrier A: 256 arrive, 224 exit, 32 spin ==============
    __syncthreads();
    if (t == 0) {
        __threadfence();                                   // release all writes
        unsigned old = atomicAdd(&subcnt[(bid >> 5) * 16], 1u);
        if (old == 31u) {
            unsigned old2 = atomicAdd(root, 1u);
            if (old2 == 7u) {                              // global releaser
                __threadfence();
                #pragma unroll
                for (int i = 0; i < 32; i++)
                    __hip_atomic_store(&flags[i * 16], 1u,
                                       __ATOMIC_RELAXED, __HIP_MEMORY_SCOPE_AGENT);
            }
        }
    }
    if (bid >= 32) return;                                 // arrive-and-exit
    if (t == 0) {
        while (__hip_atomic_load(&flags[bid * 16],
                                 __ATOMIC_RELAXED, __HIP_MEMORY_SCOPE_AGENT) < 1u)
            __builtin_amdgcn_s_sleep(8);
        __threadfence();                                   // acquire
    }
    __syncthreads();

    // =================== tail: 32 blocks x 4 graphs ===================
    float* r1 = u;            // 1024: [kq][g][f]
    float* va = u + 1024;     // 512: raw v (per layer)
    float* hn = u + 1536;     // 512: BN-normalized
    float* sc = u + 2048;     // 128
    float* sh = u + 2176;     // 128
    const int g0 = bid * 4;

    // ---- R: reduce part over 128 chunks for 4 graphs ----
    {
        const int fl4 = (t & 15) * 4;
        const int fh  = (t >> 4) & 1;
        const int gl  = (t >> 5) & 3;
        const int kq  = t >> 7;                    // 0/1 -> 32 kc each
        const float4* p = (const float4*)(part
            + (size_t)(64 * kq + fh) * 8192 + (g0 + gl) * 64 + fl4);
        float4 v = make_float4(0.f, 0.f, 0.f, 0.f);
        #pragma unroll 8
        for (int kc = 0; kc < 32; kc++) {
            float4 x4 = p[(size_t)kc * 4096];      // +2*8192 floats per kc
            v.x += x4.x; v.y += x4.y; v.z += x4.z; v.w += x4.w;
        }
        *(float4*)(r1 + kq * 512 + gl * 128 + fh * 64 + fl4) = v;
    }
    __syncthreads();
    #pragma unroll
    for (int e = t; e < 512; e += 256) {           // v0raw = relu(sum+ppart+bm0)
        int gl = e >> 7, f = e & 127;
        float s = bm0[f] + ppart[(g0 + gl) * DM + f]
                + r1[gl * 128 + f] + r1[512 + gl * 128 + f];
        va[e] = fmaxf(s, 0.f);
    }
    __syncthreads();
    if (t < 128) {                                 // stats0 partial slab
        float a0 = va[t], a1 = va[128 + t], a2 = va[256 + t], a3 = va[384 + t];
        spart0[bid * 256 + t]       = a0 + a1 + a2 + a3;
        spart0[bid * 256 + 128 + t] = a0 * a0 + a1 * a1 + a2 * a2 + a3 * a3;
    }
    tail_bar(tcnt + 0, flags, 2u, bid);

    // ---- M1 ----
    if (t < 128) {                                 // redundant stats0 reduce
        float s1 = 0.f, s2 = 0.f;
        #pragma unroll 8
        for (int b = 0; b < 32; b++) {
            s1 += spart0[b * 256 + t];
            s2 += spart0[b * 256 + 128 + t];
        }
        float m = s1 * (1.f / 128.f);
        float var = s2 * (1.f / 128.f) - m * m;
        float scv = gbn0[t] * rsqrtf(var + BN_EPS);
        sc[t] = scv; sh[t] = bbn0[t] - m * scv;
    }
    __syncthreads();
    #pragma unroll
    for (int e = t; e < 512; e += 256) {
        int k = e & 127;
        hn[e] = va[e] * sc[k] + sh[k];
    }
    __syncthreads();
    {
        const int f = t & 127, gh = t >> 7;
        float a0 = 0.f, a1 = 0.f;
        #pragma unroll 8
        for (int k = 0; k < 128; k++) {
            float w = Wm1[k * DM + f];
            a0 += hn[(gh * 2 + 0) * 128 + k] * w;
            a1 += hn[(gh * 2 + 1) * 128 + k] * w;
        }
        float bb = bm1[f];
        va[(gh * 2 + 0) * 128 + f] = fmaxf(a0 + bb, 0.f);
        va[(gh * 2 + 1) * 128 + f] = fmaxf(a1 + bb, 0.f);
    }
    __syncthreads();
    if (t < 128) {
        float a0 = va[t], a1 = va[128 + t], a2 = va[256 + t], a3 = va[384 + t];
        spart1[bid * 256 + t]       = a0 + a1 + a2 + a3;
        spart1[bid * 256 + 128 + t] = a0 * a0 + a1 * a1 + a2 * a2 + a3 * a3;
    }
    tail_bar(tcnt + 16, flags, 3u, bid);

    // ---- M2 ----
    if (t < 128) {
        float s1 = 0.f, s2 = 0.f;
        #pragma unroll 8
        for (int b = 0; b < 32; b++) {
            s1 += spart1[b * 256 + t];
            s2 += spart1[b * 256 + 128 + t];
        }
        float m = s1 * (1.f / 128.f);
        float var = s2 * (1.f / 128.f) - m * m;
        float scv = gbn1[t] * rsqrtf(var + BN_EPS);
        sc[t] = scv; sh[t] = bbn1[t] - m * scv;
    }
    __syncthreads();
    #pragma unroll
    for (int e = t; e < 512; e += 256) {
        int k = e & 127;
        hn[e] = va[e] * sc[k] + sh[k];
    }
    __syncthreads();
    {
        const int f = t & 127, gh = t >> 7;
        float a0 = 0.f, a1 = 0.f;
        #pragma unroll 8
        for (int k = 0; k < 128; k++) {
            float w = Wm2[k * DM + f];
            a0 += hn[(gh * 2 + 0) * 128 + k] * w;
            a1 += hn[(gh * 2 + 1) * 128 + k] * w;
        }
        float bb = bm2[f];
        va[(gh * 2 + 0) * 128 + f] = fmaxf(a0 + bb, 0.f);
        va[(gh * 2 + 1) * 128 + f] = fmaxf(a1 + bb, 0.f);
    }
    __syncthreads();
    if (t < 128) {
        float a0 = va[t], a1 = va[128 + t], a2 = va[256 + t], a3 = va[384 + t];
        spart2[bid * 256 + t]       = a0 + a1 + a2 + a3;
        spart2[bid * 256 + 128 + t] = a0 * a0 + a1 * a1 + a2 * a2 + a3 * a3;
    }
    tail_bar(tcnt + 32, flags, 4u, bid);

    // ---- O: BN2 + output layer ----
    if (t < 128) {
        float s1 = 0.f, s2 = 0.f;
        #pragma unroll 8
        for (int b = 0; b < 32; b++) {
            s1 += spart2[b * 256 + t];
            s2 += spart2[b * 256 + 128 + t];
        }
        float m = s1 * (1.f / 128.f);
        float var = s2 * (1.f / 128.f) - m * m;
        float scv = gbn2[t] * rsqrtf(var + BN_EPS);
        sc[t] = scv; sh[t] = bbn2[t] - m * scv;
    }
    __syncthreads();
    #pragma unroll
    for (int e = t; e < 512; e += 256) {
        int k = e & 127;
        hn[e] = va[e] * sc[k] + sh[k];
    }
    __syncthreads();
    {
        const int o = t & 63, gl = t >> 6;
        float acc = bo[o];
        #pragma unroll 8
        for (int k = 0; k < 128; k++)
            acc += hn[gl * 128 + k] * Wo[k * NOUT + o];
        out[(g0 + gl) * NOUT + o] = acc;
    }
}

extern "C" void kernel_launch(void* const* d_in, const int* in_sizes, int n_in,
                              void* d_out, int out_size, void* d_ws, size_t ws_size,
                              hipStream_t stream)
{
    const float* x   = (const float*)d_in[0];
    const float* ew  = (const float*)d_in[2];
    const float* W1  = (const float*)d_in[4];
    const float* b1  = (const float*)d_in[5];
    const float* W2  = (const float*)d_in[6];
    const float* b2  = (const float*)d_in[7];
    const float* Wm0 = (const float*)d_in[8];
    const float* bm0 = (const float*)d_in[9];
    const float* g0  = (const float*)d_in[10];
    const float* be0 = (const float*)d_in[11];
    const float* Wm1 = (const float*)d_in[12];
    const float* bm1 = (const float*)d_in[13];
    const float* g1  = (const float*)d_in[14];
    const float* be1 = (const float*)d_in[15];
    const float* Wm2 = (const float*)d_in[16];
    const float* bm2 = (const float*)d_in[17];
    const float* g2  = (const float*)d_in[18];
    const float* be2 = (const float*)d_in[19];
    const float* Wo  = (const float*)d_in[20];
    const float* bo  = (const float*)d_in[21];

    float* ws = (float*)d_ws;
    // zero barrier counters + flags (first 4 KB)
    hipMemsetAsync(d_ws, 0, 4096, stream);
    k_fused<<<256, 256, 0, stream>>>(x, ew, W1, b1, W2, b2,
                                     Wm0, bm0, g0, be0,
                                     Wm1, bm1, g1, be1,
                                     Wm2, bm2, g2, be2,
                                     Wo, bo, ws, (float*)d_out);
}